// Round 2
// baseline (726.819 us; speedup 1.0000x reference)
//
#include <hip/hip_runtime.h>
#include <stdint.h>

#define HASH_BITS 19
#define HASH_SIZE (1u << HASH_BITS)

// 8 slices of hash space: top 3 bits of idx. One slice = 64K entries * 32B
// = 2 MiB, which fits in a single XCD's 4 MiB L2. blockIdx.x & 7 lands on
// XCD (blockIdx round-robins across the 8 XCDs), so all gathers issued by
// one XCD stay inside one 2 MiB table slice -> L2-resident gather.
#define SLICE_BITS 3
#define NSLICE (1 << SLICE_BITS)

typedef float vfloat2 __attribute__((ext_vector_type(2)));
typedef float vfloat4 __attribute__((ext_vector_type(4)));
typedef uint32_t vuint4 __attribute__((ext_vector_type(4)));

__device__ __forceinline__ uint32_t bitmix_hash(float qx, float qy) {
    // q in [0,4096): float->uint truncation == floor; all intermediates
    // positive and < 2^63, so uint64 arithmetic == reference int64 exactly.
    uint64_t ix = (uint64_t)(uint32_t)qx;
    uint64_t iy = (uint64_t)(uint32_t)qy;
    uint64_t hh = ix;
    hh ^= hh >> 16;
    hh *= 2246822507ull;
    hh ^= hh >> 13;
    hh += iy * 3266489909ull;
    hh ^= hh >> 16;
    return (uint32_t)hh & (HASH_SIZE - 1);
}

// ---------------- K1: pos -> idx buffer (pure streams) ----------------
__global__ __launch_bounds__(256) void hash_kernel(
    const vfloat2* __restrict__ pos,   // N float2
    uint32_t* __restrict__ idx,        // N u32 (workspace)
    int n)
{
    int t = blockIdx.x * blockDim.x + threadIdx.x;
    int i0 = t * 4;
    if (i0 + 4 <= n) {
        // 4 positions = two 16B nt loads
        const vfloat4* p4 = (const vfloat4*)pos;
        vfloat4 a = __builtin_nontemporal_load(&p4[(size_t)t * 2]);
        vfloat4 b = __builtin_nontemporal_load(&p4[(size_t)t * 2 + 1]);
        vuint4 v;
        v.x = bitmix_hash(a.x, a.y);
        v.y = bitmix_hash(a.z, a.w);
        v.z = bitmix_hash(b.x, b.y);
        v.w = bitmix_hash(b.z, b.w);
        // regular store: we WANT idx resident in L2/L3 for K2's re-reads
        *(vuint4*)&idx[i0] = v;
    } else if (i0 < n) {
        for (int i = i0; i < n; ++i) {
            vfloat2 q = __builtin_nontemporal_load(&pos[i]);
            idx[i] = bitmix_hash(q.x, q.y);
        }
    }
}

// ---------------- K2: slice-predicated gather ----------------
// Block (c = blockIdx>>3, s = blockIdx&7): scan chunk c of idx, gather+write
// only items whose slice == s. Each item is written by exactly one block.
// Chunk = 256 threads * 4 items = 1024 items; the 8 slice-blocks of a chunk
// are dispatched consecutively -> same idx lines read ~simultaneously by all
// 8 XCDs -> L3 shares the idx stream across them.
__global__ __launch_bounds__(256) void gather_kernel(
    const uint32_t* __restrict__ idx,  // N u32
    const vfloat4* __restrict__ table, // HASH_SIZE*2 float4
    vfloat4* __restrict__ out,         // 2N float4
    int n)
{
    const uint32_t s = blockIdx.x & (NSLICE - 1);
    const uint32_t c = blockIdx.x >> SLICE_BITS;
    const int i0 = (int)(c * (256 * 4) + threadIdx.x * 4);
    if (i0 >= n) return;

    vuint4 v;
    if (i0 + 4 <= n) {
        v = *(const vuint4*)&idx[i0];   // regular load: share via L2/L3
    } else {
        v.x = v.y = v.z = v.w = 0xFFFFFFFFu;  // slice 0x1F.. matches nothing
        for (int j = 0; j < 4; ++j)
            if (i0 + j < n) v[j] = idx[i0 + j];
    }

#pragma unroll
    for (int j = 0; j < 4; ++j) {
        uint32_t id = v[j];
        if ((id >> (HASH_BITS - SLICE_BITS)) == s) {
            size_t e = (size_t)id * 2;
            vfloat4 lo = table[e];       // L2-resident slice (regular load)
            vfloat4 hi = table[e + 1];
            size_t o = (size_t)(i0 + j) * 2;
            __builtin_nontemporal_store(lo, &out[o]);
            __builtin_nontemporal_store(hi, &out[o + 1]);
        }
    }
}

// ---------------- fallback: round-1 single-kernel (if ws too small) ----------------
__global__ __launch_bounds__(256) void hashgrid2d_fallback(
    const vfloat2* __restrict__ pos,
    const vfloat4* __restrict__ table,
    vfloat4* __restrict__ out,
    int n)
{
    long long t = (long long)blockIdx.x * blockDim.x + threadIdx.x;
    long long nitems = 2LL * n;
    long long stride = (long long)gridDim.x * blockDim.x;
    for (; t < nitems; t += stride) {
        long long p = t >> 1;
        int h = (int)(t & 1);
        vfloat2 q = __builtin_nontemporal_load(&pos[p]);
        uint32_t id = bitmix_hash(q.x, q.y);
        vfloat4 vv = table[(size_t)id * 2 + h];
        __builtin_nontemporal_store(vv, &out[(size_t)p * 2 + h]);
    }
}

extern "C" void kernel_launch(void* const* d_in, const int* in_sizes, int n_in,
                              void* d_out, int out_size, void* d_ws, size_t ws_size,
                              hipStream_t stream) {
    const vfloat2* pos   = (const vfloat2*)d_in[0];   // positions [N,2]
    const vfloat4* table = (const vfloat4*)d_in[1];   // table [HASH_SIZE,8]
    vfloat4* out         = (vfloat4*)d_out;           // [N,8] as 2N float4

    int n = in_sizes[0] / 2;  // N positions

    if (ws_size >= (size_t)n * sizeof(uint32_t)) {
        uint32_t* idx = (uint32_t*)d_ws;

        int block = 256;
        // K1: 4 items/thread
        int threads1 = (n + 3) / 4;
        int grid1 = (threads1 + block - 1) / block;
        hash_kernel<<<grid1, block, 0, stream>>>(pos, idx, n);

        // K2: chunks of 1024 items, x8 slices
        int chunks = (n + 1023) / 1024;
        long long grid2 = (long long)chunks * NSLICE;
        gather_kernel<<<(int)grid2, block, 0, stream>>>(idx, table, out, n);
    } else {
        long long nitems = 2LL * n;
        int block = 256;
        long long need = (nitems + block - 1) / block;
        int grid = (int)(need < 2048 ? need : 2048);
        hashgrid2d_fallback<<<grid, block, 0, stream>>>(pos, table, out, n);
    }
}

// Round 3
// 495.487 us; speedup vs baseline: 1.4669x; 1.4669x over previous
//
#include <hip/hip_runtime.h>
#include <stdint.h>

#define HASH_BITS 19
#define HASH_SIZE (1u << HASH_BITS)

// Temporal slicing: 8 phases over the top-3 bits of hash space. During phase
// s, ALL blocks on ALL XCDs gather only from slice s (64K entries * 32B =
// 2 MiB). The instantaneous global hot set is 2 MiB -> fits every XCD L2 and
// trivially survives in the 256 MiB L3 between phases, instead of keeping
// the whole 16 MiB table hot for the whole kernel (which L3 demonstrably
// failed to hold: R1 measured 378 MB of table HBM fetch).
#define SLICE_BITS 3
#define NSLICE (1 << SLICE_BITS)
#define SLICE_SHIFT (HASH_BITS - SLICE_BITS)   // idx>>16 = slice id

#define BLOCK 256
#define IPT 8                        // items per thread
#define CHUNK (BLOCK * IPT)          // 2048 items per block-chunk
// LDS value buffer: CHUNK * 32B = 64 KiB -> 2 blocks/CU (160 KiB budget).

typedef float vfloat2 __attribute__((ext_vector_type(2)));
typedef float vfloat4 __attribute__((ext_vector_type(4)));

__device__ __forceinline__ uint32_t bitmix_hash(float qx, float qy) {
    // q in [0,4096): float->uint truncation == floor; all intermediates
    // positive and < 2^63, so uint64 arithmetic == reference int64 exactly.
    uint64_t ix = (uint64_t)(uint32_t)qx;
    uint64_t iy = (uint64_t)(uint32_t)qy;
    uint64_t hh = ix;
    hh ^= hh >> 16;
    hh *= 2246822507ull;
    hh ^= hh >> 13;
    hh += iy * 3266489909ull;
    hh ^= hh >> 16;
    return (uint32_t)hh & (HASH_SIZE - 1);
}

// Persistent grid (512 blocks = 2/CU): all blocks start together and do
// identical per-chunk work, so they sweep phases in rough lockstep -- that
// lockstep is what keeps the global hot slice small. Values are staged in
// LDS so the output store is dense full-line nt (no R2-style sparse-write
// amplification), issued once per chunk after all phases complete.
__global__ __launch_bounds__(BLOCK) void hashgrid2d_phased(
    const vfloat2* __restrict__ pos,   // N float2
    const vfloat4* __restrict__ table, // HASH_SIZE*2 float4
    vfloat4* __restrict__ out,         // 2N float4
    int n, int nchunks)
{
    __shared__ vfloat4 vals[CHUNK * 2];   // 64 KiB: 2 float4 per item
    const int t = threadIdx.x;

    for (int c = blockIdx.x; c < nchunks; c += gridDim.x) {
        const long long base = (long long)c * CHUNK;

        // ---- 1) stream pos, hash into registers ----
        uint32_t idx[IPT];
#pragma unroll
        for (int j = 0; j < IPT; ++j) {
            long long g = base + j * BLOCK + t;     // coalesced per j
            if (g < n) {
                vfloat2 q = __builtin_nontemporal_load(&pos[g]);
                idx[j] = bitmix_hash(q.x, q.y);
            } else {
                idx[j] = 0xFFFFFFFFu;               // slice 0xFFFF: no phase
            }
        }

        __syncthreads();   // WAR: prev chunk's LDS reads done before rewrite

        // ---- 2) phased gather into LDS ----
        // #pragma unroll 1: keep phases temporally separated -- unrolling
        // would let the scheduler interleave gathers of different slices and
        // defeat the working-set concentration.
#pragma unroll 1
        for (uint32_t s = 0; s < NSLICE; ++s) {
#pragma unroll
            for (int j = 0; j < IPT; ++j) {
                if ((idx[j] >> SLICE_SHIFT) == s) {
                    size_t e = (size_t)idx[j] * 2;
                    vfloat4 lo = table[e];          // L2/L3-resident slice
                    vfloat4 hi = table[e + 1];
                    int li = j * BLOCK + t;         // chunk-local item
                    vals[li * 2]     = lo;
                    vals[li * 2 + 1] = hi;
                }
            }
        }

        __syncthreads();   // RAW: all gathers deposited before dense store

        // ---- 3) dense full-line nt store of the whole chunk ----
        // float4-granule f in [0, CHUNK*2); item = f>>1; fully coalesced.
#pragma unroll
        for (int k = 0; k < IPT * 2; ++k) {
            int f = k * BLOCK + t;
            long long item = base + (f >> 1);
            if (item < n)
                __builtin_nontemporal_store(vals[f], &out[base * 2 + f]);
        }
    }
}

extern "C" void kernel_launch(void* const* d_in, const int* in_sizes, int n_in,
                              void* d_out, int out_size, void* d_ws, size_t ws_size,
                              hipStream_t stream) {
    const vfloat2* pos   = (const vfloat2*)d_in[0];   // positions [N,2]
    const vfloat4* table = (const vfloat4*)d_in[1];   // table [HASH_SIZE,8]
    vfloat4* out         = (vfloat4*)d_out;           // [N,8] as 2N float4

    int n = in_sizes[0] / 2;  // N positions
    int nchunks = (int)(((long long)n + CHUNK - 1) / CHUNK);
    int grid = nchunks < 512 ? nchunks : 512;   // 2 blocks/CU, persistent
    hashgrid2d_phased<<<grid, BLOCK, 0, stream>>>(pos, table, out, n, nchunks);
}